// Round 7
// baseline (254.161 us; speedup 1.0000x reference)
//
#include <hip/hip_runtime.h>
#include <cmath>

#define BB  1024
#define TT  128
#define HH1 512
#define HH2 256
#define CC  18

// d_ws layout (byte offsets)
#define WS_DIG   0ull             // W2 digits: 8x4x16x2x32x16 i8 = 512 KB
#define WS_W3D   524288ull        // W3 digits LDS image: 32 KB
#define WS_MASK  557056ull        // s1 masks[t][row][8 u64] = 8 MB
#define WS_MASK2 8945664ull       // s2 masks[t][row][8 u32] = 4 MB
#define WS_D3    13139968ull      // D3[t][row][c<18] fp32 = 9.4 MB (end ~22.6 MB)

typedef int  v4i  __attribute__((ext_vector_type(4)));
typedef int  v16i __attribute__((ext_vector_type(16)));
typedef unsigned long long ull;

__device__ __forceinline__ v4i expand_bits(unsigned bits) {
  v4i a;
  a.x = (int)((( bits        & 15u) * 0x204081u) & 0x01010101u);
  a.y = (int)((((bits >>  4) & 15u) * 0x204081u) & 0x01010101u);
  a.z = (int)((((bits >>  8) & 15u) * 0x204081u) & 0x01010101u);
  a.w = (int)((((bits >> 12) & 15u) * 0x204081u) & 0x01010101u);
  return a;
}

// ---- prep: W2 fp32 -> 4 signed-i8 digit planes of llrint(w*2^32), laid out
// [stripe(8)][d(4)][s(16)][h(2)][n(32)][j(16)]; h1 = s*32+h*16+j, h2 = stripe*32+n.
__global__ __launch_bounds__(256) void prep_digits(const float* __restrict__ W2,
                                                   signed char* __restrict__ out)
{
  int i = blockIdx.x * 256 + threadIdx.x;         // [0, 524288)
  int j = i & 15, n = (i >> 4) & 31, h = (i >> 9) & 1;
  int s = (i >> 10) & 15, d = (i >> 14) & 3, st = i >> 16;
  int h1 = s * 32 + h * 16 + j;
  int h2 = st * 32 + n;
  float w = W2[h2 * HH1 + h1];
  long long ll = llrint((double)w * 4294967296.0);
  int v = (int)ll;
  signed char d0 = (signed char)(v & 255); v = (v - d0) >> 8;
  signed char d1 = (signed char)(v & 255); v = (v - d1) >> 8;
  signed char d2 = (signed char)(v & 255); v = (v - d2) >> 8;
  signed char d3 = (signed char)v;
  signed char dig = (d == 0) ? d0 : (d == 1) ? d1 : (d == 2) ? d2 : d3;
  out[i] = dig;
}

// ---- prep W3 digits, LDS image [d(4)][c8(8)][h(2)][col(32)][j(16)], 32 KB.
__global__ __launch_bounds__(256) void prep_w3dig(const float* __restrict__ W3,
                                                  signed char* __restrict__ out)
{
  int i = blockIdx.x * 256 + threadIdx.x;         // [0, 32768)
  int j = i & 15, col = (i >> 4) & 31, h = (i >> 9) & 1;
  int c8 = (i >> 10) & 7, d = (i >> 13) & 3;
  int h2 = c8 * 32 + h * 16 + j;
  float w = (col < CC) ? W3[col * HH2 + h2] : 0.0f;
  long long ll = llrint((double)w * 4294967296.0);
  int v = (int)ll;
  signed char d0 = (signed char)(v & 255); v = (v - d0) >> 8;
  signed char d1 = (signed char)(v & 255); v = (v - d1) >> 8;
  signed char d2 = (signed char)(v & 255); v = (v - d2) >> 8;
  signed char d3 = (signed char)v;
  signed char dig = (d == 0) ? d0 : (d == 1) ? d1 : (d == 2) ? d2 : d3;
  out[i] = dig;
}

// ---- phase A: bit-exact layer-1 spike masks for all (row,t). One block/row.
__global__ __launch_bounds__(256) void phase_s1(const float* __restrict__ x,
    const float* __restrict__ W1, const float* __restrict__ b1,
    ull* __restrict__ masks)
{
  __shared__ float xrow[TT];
  int row = blockIdx.x, tid = threadIdx.x, wv = tid >> 6, lane = tid & 63;
  for (int i = tid; i < TT; i += 256) xrow[i] = x[row * TT + i];
  const float w1a = W1[tid], w1b = W1[tid + 256];
  const float b1a = b1[tid], b1b = b1[tid + 256];
  float v1a = 0.f, v1b = 0.f;
  __syncthreads();
  for (int t = 0; t < TT; ++t) {
    float xt = xrow[t];
    float iA = __fadd_rn(__fmul_rn(xt, w1a), b1a);
    v1a = __fadd_rn(v1a, iA);
    bool sA = (v1a >= 1.0f);  v1a = sA ? (v1a - 1.0f) : v1a;
    float iB = __fadd_rn(__fmul_rn(xt, w1b), b1b);
    v1b = __fadd_rn(v1b, iB);
    bool sB = (v1b >= 1.0f);  v1b = sB ? (v1b - 1.0f) : v1b;
    ull mA = __ballot(sA);
    ull mB = __ballot(sB);
    if (lane == 0) {
      ull* p = masks + ((size_t)t * BB + row) * 8;
      p[wv] = mA; p[4 + wv] = mB;
    }
  }
}

// ---- fused layer 2: exact i8-MFMA GEMM + in-LDS v2 scan; D2 never leaves
// the CU. grid 256 = rowtile(32) x stripe(8); block = 32 rows x 32 cols x 128 t.
// Chunks of 16 t: waves compute 4 t each (full K=512, 4 digit planes at once,
// 2-t B-register reuse), stash d2 in LDS, barrier, 256 threads scan.
__global__ __launch_bounds__(256, 1) void phase_gemmscan(
    const signed char* __restrict__ Bd, const ull* __restrict__ masks,
    const float* __restrict__ b2, unsigned* __restrict__ masks2)
{
  __shared__ __align__(16) signed char Bl[65536];
  __shared__ float d2buf[16 * 1024];               // [tl][rowl*32+col], 64 KB

  const int bid = blockIdx.x;
  const int stripe = bid & 7, rowtile = bid >> 3;  // 8 stripes x 32 rowtiles
  const int tid = threadIdx.x, lane = tid & 63, wv = tid >> 6;
  const int half = lane >> 5;

  {
    const uint4* src = (const uint4*)(Bd + (size_t)stripe * 65536);
    uint4* dst = (uint4*)Bl;
#pragma unroll
    for (int i = 0; i < 16; ++i) dst[tid + 256 * i] = src[tid + 256 * i];
  }

  const int arow = rowtile * 32 + (lane & 31);
  const int hsh  = half * 16;
  const signed char* bbase = Bl + half * 512 + (lane & 31) * 16;

  const int scol = tid & 31;                       // scan: local col
  const int sgrp = tid >> 5;                       // scan: row group (4 rows)
  const float b2r = b2[stripe * 32 + scol];
  float v2[4] = {0.f, 0.f, 0.f, 0.f};

  __syncthreads();

  for (int c = 0; c < 8; ++c) {                    // 16-t chunks
    const int tb = c * 16;
#pragma unroll
    for (int g = 0; g < 2; ++g) {                  // wave w: t = tb+8g+w, +4
      const int tA = tb + 8 * g + wv, tB = tA + 4;
      ull wA[8], wB[8];
      { const ull* p = masks + ((size_t)tA * BB + arow) * 8;
#pragma unroll
        for (int k = 0; k < 8; ++k) wA[k] = p[k]; }
      { const ull* p = masks + ((size_t)tB * BB + arow) * 8;
#pragma unroll
        for (int k = 0; k < 8; ++k) wB[k] = p[k]; }

      v16i accA[4], accB[4];
#pragma unroll
      for (int d = 0; d < 4; ++d) {
        accA[d] = (v16i){0,0,0,0,0,0,0,0,0,0,0,0,0,0,0,0};
        accB[d] = (v16i){0,0,0,0,0,0,0,0,0,0,0,0,0,0,0,0};
      }
#pragma unroll
      for (int s = 0; s < 16; ++s) {
        v4i q0 = *(const v4i*)(bbase + (0 * 16 + s) * 1024);
        v4i q1 = *(const v4i*)(bbase + (1 * 16 + s) * 1024);
        v4i q2 = *(const v4i*)(bbase + (2 * 16 + s) * 1024);
        v4i q3 = *(const v4i*)(bbase + (3 * 16 + s) * 1024);
        unsigned shift = ((s & 1) << 5) + hsh;
        v4i aA = expand_bits((unsigned)(wA[s >> 1] >> shift) & 0xFFFFu);
        v4i aB = expand_bits((unsigned)(wB[s >> 1] >> shift) & 0xFFFFu);
        accA[0] = __builtin_amdgcn_mfma_i32_32x32x32_i8(aA, q0, accA[0], 0, 0, 0);
        accB[0] = __builtin_amdgcn_mfma_i32_32x32x32_i8(aB, q0, accB[0], 0, 0, 0);
        accA[1] = __builtin_amdgcn_mfma_i32_32x32x32_i8(aA, q1, accA[1], 0, 0, 0);
        accB[1] = __builtin_amdgcn_mfma_i32_32x32x32_i8(aB, q1, accB[1], 0, 0, 0);
        accA[2] = __builtin_amdgcn_mfma_i32_32x32x32_i8(aA, q2, accA[2], 0, 0, 0);
        accB[2] = __builtin_amdgcn_mfma_i32_32x32x32_i8(aB, q2, accB[2], 0, 0, 0);
        accA[3] = __builtin_amdgcn_mfma_i32_32x32x32_i8(aA, q3, accA[3], 0, 0, 0);
        accB[3] = __builtin_amdgcn_mfma_i32_32x32x32_i8(aB, q3, accB[3], 0, 0, 0);
      }
      // epilogue: exact digit fold -> one f32 rounding (bit-identical to R4)
#pragma unroll
      for (int r = 0; r < 16; ++r) {
        int sloA = accA[0][r] + (accA[1][r] << 8);   // |.| < 2^25, exact i32
        int shiA = accA[2][r] + (accA[3][r] << 8);
        double ssA = fma((double)shiA, 65536.0, (double)sloA);  // exact
        float dA = (float)(ssA * 0x1p-32);                      // one rounding
        int sloB = accB[0][r] + (accB[1][r] << 8);
        int shiB = accB[2][r] + (accB[3][r] << 8);
        double ssB = fma((double)shiB, 65536.0, (double)sloB);
        float dB = (float)(ssB * 0x1p-32);
        int rowl = (r & 3) + 8 * (r >> 2) + 4 * half;
        d2buf[(tA - tb) * 1024 + rowl * 32 + (lane & 31)] = dA;
        d2buf[(tB - tb) * 1024 + rowl * 32 + (lane & 31)] = dB;
      }
    }
    __syncthreads();                               // d2buf complete for chunk

    for (int tl = 0; tl < 16; ++tl) {
      const int t = tb + tl;
#pragma unroll
      for (int q = 0; q < 4; ++q) {
        float d2 = d2buf[tl * 1024 + (sgrp * 4 + q) * 32 + scol];
        float i2 = __fadd_rn(d2, b2r);
        v2[q] = __fadd_rn(v2[q], i2);
        bool s2 = (v2[q] >= 1.0f);
        v2[q] = s2 ? (v2[q] - 1.0f) : v2[q];
        ull m = __ballot(s2);                      // lo32: row 8w+q, hi32: 8w+4+q
        if (lane == 0)
          masks2[((size_t)t * BB + rowtile * 32 + wv * 8 + q) * 8 + stripe]
              = (unsigned)m;
        else if (lane == 32)
          masks2[((size_t)t * BB + rowtile * 32 + wv * 8 + 4 + q) * 8 + stripe]
              = (unsigned)(m >> 32);
      }
    }
    __syncthreads();                               // before next chunk's writes
  }
}

// ---- layer 3: D3[t] = S2[t] @ W3^T, exact i8 MFMA. Block: 32 rows x 4 t.
__global__ __launch_bounds__(256) void phase_l3(const signed char* __restrict__ W3d,
    const unsigned* __restrict__ masks2, float* __restrict__ D3)
{
  __shared__ __align__(16) signed char Bl[32768];
  const int bid = blockIdx.x;
  const int rowtile = bid & 31, tgrp = bid >> 5;
  const int tid = threadIdx.x, lane = tid & 63, wv = tid >> 6;
  const int half = lane >> 5;
  const int t = tgrp * 4 + wv;
  const int row = rowtile * 32 + (lane & 31);

  {
    const uint4* src = (const uint4*)W3d;
    uint4* dst = (uint4*)Bl;
#pragma unroll
    for (int i = 0; i < 8; ++i) dst[tid + 256 * i] = src[tid + 256 * i];
  }

  unsigned words[8];
  {
    const unsigned* mp = masks2 + ((size_t)t * BB + row) * 8;
#pragma unroll
    for (int k = 0; k < 8; ++k) words[k] = mp[k];
  }
  __syncthreads();

  const signed char* bbase = Bl + half * 512 + (lane & 31) * 16;
  v16i acc[4];
#pragma unroll
  for (int d = 0; d < 4; ++d) acc[d] = (v16i){0,0,0,0,0,0,0,0,0,0,0,0,0,0,0,0};

#pragma unroll
  for (int c8 = 0; c8 < 8; ++c8) {
    v4i a = expand_bits((words[c8] >> (half * 16)) & 0xFFFFu);
#pragma unroll
    for (int d = 0; d < 4; ++d) {
      v4i b = *(const v4i*)(bbase + ((d * 8 + c8) * 2) * 512);
      acc[d] = __builtin_amdgcn_mfma_i32_32x32x32_i8(a, b, acc[d], 0, 0, 0);
    }
  }

  const int col = lane & 31;
#pragma unroll
  for (int r = 0; r < 16; ++r) {
    int slo = acc[0][r] + (acc[1][r] << 8);
    int shi = acc[2][r] + (acc[3][r] << 8);
    double ss = fma((double)shi, 65536.0, (double)slo);
    float d3v = (float)(ss * 0x1p-32);
    int rowl = (r & 3) + 8 * (r >> 2) + 4 * half;
    int grow = rowtile * 32 + rowl;
    if (col < CC) D3[((size_t)t * BB + grow) * CC + col] = d3v;
  }
}

// ---- v3/acc scan + output. thread=(row,c); coalesced; grid 72.
__global__ __launch_bounds__(256) void phase_v3(const float* __restrict__ D3,
    const float* __restrict__ b3, float* __restrict__ out)
{
  int g = blockIdx.x * 256 + threadIdx.x;         // [0, 18432)
  int row = g / CC, c = g - row * CC;
  const float b3r = b3[c];
  float v3 = 0.f, acc = 0.f;
  float d3 = D3[g];
  for (int t = 0; t < TT; ++t) {
    int tn = (t + 1 < TT) ? t + 1 : t;
    float d3n = D3[(size_t)tn * (BB * CC) + g];   // prefetch
    float i3 = __fadd_rn(d3, b3r);
    v3 = __fadd_rn(v3, i3);
    bool s3 = (v3 >= 1.0f);  v3 = s3 ? (v3 - 1.0f) : v3;
    acc = __fadd_rn(acc, s3 ? 1.0f : 0.0f);
    d3 = d3n;
  }
  out[g] = acc * (1.0f / TT);
}

extern "C" void kernel_launch(void* const* d_in, const int* in_sizes, int n_in,
                              void* d_out, int out_size, void* d_ws, size_t ws_size,
                              hipStream_t stream)
{
  (void)in_sizes; (void)n_in; (void)out_size; (void)ws_size;
  const float* x  = (const float*)d_in[0];
  const float* W1 = (const float*)d_in[1];
  const float* b1 = (const float*)d_in[2];
  const float* W2 = (const float*)d_in[3];
  const float* b2 = (const float*)d_in[4];
  const float* W3 = (const float*)d_in[5];
  const float* b3 = (const float*)d_in[6];
  // d_in[7] = repeat (structurally 1 for this problem shape)
  float* out = (float*)d_out;
  char*  ws  = (char*)d_ws;

  signed char* dig    = (signed char*)(ws + WS_DIG);
  signed char* w3dig  = (signed char*)(ws + WS_W3D);
  ull*         masks  = (ull*)(ws + WS_MASK);
  unsigned*    masks2 = (unsigned*)(ws + WS_MASK2);
  float*       D3     = (float*)(ws + WS_D3);

  prep_digits<<<2048, 256, 0, stream>>>(W2, dig);
  prep_w3dig<<<128, 256, 0, stream>>>(W3, w3dig);
  phase_s1<<<1024, 256, 0, stream>>>(x, W1, b1, masks);
  phase_gemmscan<<<256, 256, 0, stream>>>(dig, masks, b2, masks2);
  phase_l3<<<1024, 256, 0, stream>>>(w3dig, masks2, D3);
  phase_v3<<<72, 256, 0, stream>>>(D3, b3, out);
}

// Round 8
// 230.586 us; speedup vs baseline: 1.1022x; 1.1022x over previous
//
#include <hip/hip_runtime.h>
#include <cmath>

#define BB  1024
#define TT  128
#define HH1 512
#define HH2 256
#define CC  18

// d_ws layout (byte offsets)
#define WS_DIG   0ull             // W2 digits: 8x4x16x2x32x16 i8 = 512 KB
#define WS_W3D   524288ull        // W3 digits LDS image: 32 KB
#define WS_MASK  557056ull        // s1 masks[t][row][8 u64] = 8 MB
#define WS_MASK2 8945664ull       // s2 masks[t][row][8 u32] = 4 MB
#define WS_D3    13139968ull      // D3[t][row][c<18] fp32 = 9.4 MB (end ~22.6 MB)

typedef int  v4i  __attribute__((ext_vector_type(4)));
typedef int  v16i __attribute__((ext_vector_type(16)));
typedef unsigned long long ull;

__device__ __forceinline__ v4i expand_bits(unsigned bits) {
  v4i a;
  a.x = (int)((( bits        & 15u) * 0x204081u) & 0x01010101u);
  a.y = (int)((((bits >>  4) & 15u) * 0x204081u) & 0x01010101u);
  a.z = (int)((((bits >>  8) & 15u) * 0x204081u) & 0x01010101u);
  a.w = (int)((((bits >> 12) & 15u) * 0x204081u) & 0x01010101u);
  return a;
}

// ---- prep: W2 fp32 -> 4 signed-i8 digit planes of llrint(w*2^32), laid out
// [stripe(8)][d(4)][s(16)][h(2)][n(32)][j(16)]; h1 = s*32+h*16+j, h2 = stripe*32+n.
__global__ __launch_bounds__(256) void prep_digits(const float* __restrict__ W2,
                                                   signed char* __restrict__ out)
{
  int i = blockIdx.x * 256 + threadIdx.x;         // [0, 524288)
  int j = i & 15, n = (i >> 4) & 31, h = (i >> 9) & 1;
  int s = (i >> 10) & 15, d = (i >> 14) & 3, st = i >> 16;
  int h1 = s * 32 + h * 16 + j;
  int h2 = st * 32 + n;
  float w = W2[h2 * HH1 + h1];
  long long ll = llrint((double)w * 4294967296.0);
  int v = (int)ll;
  signed char d0 = (signed char)(v & 255); v = (v - d0) >> 8;
  signed char d1 = (signed char)(v & 255); v = (v - d1) >> 8;
  signed char d2 = (signed char)(v & 255); v = (v - d2) >> 8;
  signed char d3 = (signed char)v;
  signed char dig = (d == 0) ? d0 : (d == 1) ? d1 : (d == 2) ? d2 : d3;
  out[i] = dig;
}

// ---- prep W3 digits, LDS image [d(4)][c8(8)][h(2)][col(32)][j(16)], 32 KB.
__global__ __launch_bounds__(256) void prep_w3dig(const float* __restrict__ W3,
                                                  signed char* __restrict__ out)
{
  int i = blockIdx.x * 256 + threadIdx.x;         // [0, 32768)
  int j = i & 15, col = (i >> 4) & 31, h = (i >> 9) & 1;
  int c8 = (i >> 10) & 7, d = (i >> 13) & 3;
  int h2 = c8 * 32 + h * 16 + j;
  float w = (col < CC) ? W3[col * HH2 + h2] : 0.0f;
  long long ll = llrint((double)w * 4294967296.0);
  int v = (int)ll;
  signed char d0 = (signed char)(v & 255); v = (v - d0) >> 8;
  signed char d1 = (signed char)(v & 255); v = (v - d1) >> 8;
  signed char d2 = (signed char)(v & 255); v = (v - d2) >> 8;
  signed char d3 = (signed char)v;
  signed char dig = (d == 0) ? d0 : (d == 1) ? d1 : (d == 2) ? d2 : d3;
  out[i] = dig;
}

// ---- phase A: bit-exact layer-1 spike masks for all (row,t). One block/row.
__global__ __launch_bounds__(256) void phase_s1(const float* __restrict__ x,
    const float* __restrict__ W1, const float* __restrict__ b1,
    ull* __restrict__ masks)
{
  __shared__ float xrow[TT];
  int row = blockIdx.x, tid = threadIdx.x, wv = tid >> 6, lane = tid & 63;
  for (int i = tid; i < TT; i += 256) xrow[i] = x[row * TT + i];
  const float w1a = W1[tid], w1b = W1[tid + 256];
  const float b1a = b1[tid], b1b = b1[tid + 256];
  float v1a = 0.f, v1b = 0.f;
  __syncthreads();
  for (int t = 0; t < TT; ++t) {
    float xt = xrow[t];
    float iA = __fadd_rn(__fmul_rn(xt, w1a), b1a);
    v1a = __fadd_rn(v1a, iA);
    bool sA = (v1a >= 1.0f);  v1a = sA ? (v1a - 1.0f) : v1a;
    float iB = __fadd_rn(__fmul_rn(xt, w1b), b1b);
    v1b = __fadd_rn(v1b, iB);
    bool sB = (v1b >= 1.0f);  v1b = sB ? (v1b - 1.0f) : v1b;
    ull mA = __ballot(sA);
    ull mB = __ballot(sB);
    if (lane == 0) {
      ull* p = masks + ((size_t)t * BB + row) * 8;
      p[wv] = mA; p[4 + wv] = mB;
    }
  }
}

// ---- fused layer 2: producer-consumer. 512 threads = 8 waves.
// Waves 0-3: exact i8-MFMA GEMM for chunk c (8 t; wave wv owns t = tb+wv and
// tb+4+wv, full K=512, 4 digit planes) into d2buf[c&1].
// Waves 4-7: v2-scan of chunk c-1 from d2buf[1-(c&1)] -> s2 ballot masks.
// One __syncthreads per chunk; GEMM and scan overlap across wave groups.
__global__ __launch_bounds__(512, 2) void phase_gemmscan(
    const signed char* __restrict__ Bd, const ull* __restrict__ masks,
    const float* __restrict__ b2, unsigned* __restrict__ masks2)
{
  __shared__ __align__(16) signed char Bl[65536];
  __shared__ float d2buf[2][8 * 1024];             // 2 x 32 KB

  const int bid = blockIdx.x;
  const int stripe = bid & 7, rowtile = bid >> 3;  // 8 stripes x 32 rowtiles
  const int tid = threadIdx.x, lane = tid & 63, wv = tid >> 6;
  const int half = lane >> 5;

  {
    const uint4* src = (const uint4*)(Bd + (size_t)stripe * 65536);
    uint4* dst = (uint4*)Bl;
#pragma unroll
    for (int i = 0; i < 8; ++i) dst[tid + 512 * i] = src[tid + 512 * i];
  }

  // GEMM-wave constants (wv < 4)
  const int arow = rowtile * 32 + (lane & 31);
  const int hsh  = half * 16;
  const signed char* bbase = Bl + half * 512 + (lane & 31) * 16;

  // scan-wave constants (wv >= 4)
  const int stid = tid & 255;                      // 0..255 for waves 4-7
  const int scol = stid & 31, sgrp = stid >> 5;    // col, 4-row group
  float v2[4] = {0.f, 0.f, 0.f, 0.f};
  float b2r = 0.f;
  if (wv >= 4) b2r = b2[stripe * 32 + scol];

  __syncthreads();                                 // Bl ready

  for (int c = 0; c < 17; ++c) {
    if (wv < 4 && c < 16) {
      const int tb = c * 8;
      const int tA = tb + wv, tB = tb + 4 + wv;
      ull wA[8], wB[8];
      { const ull* p = masks + ((size_t)tA * BB + arow) * 8;
#pragma unroll
        for (int k = 0; k < 8; ++k) wA[k] = p[k]; }
      { const ull* p = masks + ((size_t)tB * BB + arow) * 8;
#pragma unroll
        for (int k = 0; k < 8; ++k) wB[k] = p[k]; }

      v16i accA[4], accB[4];
#pragma unroll
      for (int d = 0; d < 4; ++d) {
        accA[d] = (v16i){0,0,0,0,0,0,0,0,0,0,0,0,0,0,0,0};
        accB[d] = (v16i){0,0,0,0,0,0,0,0,0,0,0,0,0,0,0,0};
      }
#pragma unroll
      for (int s = 0; s < 16; ++s) {
        v4i q0 = *(const v4i*)(bbase + (0 * 16 + s) * 1024);
        v4i q1 = *(const v4i*)(bbase + (1 * 16 + s) * 1024);
        v4i q2 = *(const v4i*)(bbase + (2 * 16 + s) * 1024);
        v4i q3 = *(const v4i*)(bbase + (3 * 16 + s) * 1024);
        unsigned shift = ((s & 1) << 5) + hsh;
        v4i aA = expand_bits((unsigned)(wA[s >> 1] >> shift) & 0xFFFFu);
        v4i aB = expand_bits((unsigned)(wB[s >> 1] >> shift) & 0xFFFFu);
        accA[0] = __builtin_amdgcn_mfma_i32_32x32x32_i8(aA, q0, accA[0], 0, 0, 0);
        accB[0] = __builtin_amdgcn_mfma_i32_32x32x32_i8(aB, q0, accB[0], 0, 0, 0);
        accA[1] = __builtin_amdgcn_mfma_i32_32x32x32_i8(aA, q1, accA[1], 0, 0, 0);
        accB[1] = __builtin_amdgcn_mfma_i32_32x32x32_i8(aB, q1, accB[1], 0, 0, 0);
        accA[2] = __builtin_amdgcn_mfma_i32_32x32x32_i8(aA, q2, accA[2], 0, 0, 0);
        accB[2] = __builtin_amdgcn_mfma_i32_32x32x32_i8(aB, q2, accB[2], 0, 0, 0);
        accA[3] = __builtin_amdgcn_mfma_i32_32x32x32_i8(aA, q3, accA[3], 0, 0, 0);
        accB[3] = __builtin_amdgcn_mfma_i32_32x32x32_i8(aB, q3, accB[3], 0, 0, 0);
      }
      // exact digit fold -> one f32 rounding (bit-identical to R4 path)
      float* buf = d2buf[c & 1];
#pragma unroll
      for (int r = 0; r < 16; ++r) {
        int sloA = accA[0][r] + (accA[1][r] << 8);
        int shiA = accA[2][r] + (accA[3][r] << 8);
        double ssA = fma((double)shiA, 65536.0, (double)sloA);  // exact
        float dA = (float)(ssA * 0x1p-32);                      // one rounding
        int sloB = accB[0][r] + (accB[1][r] << 8);
        int shiB = accB[2][r] + (accB[3][r] << 8);
        double ssB = fma((double)shiB, 65536.0, (double)sloB);
        float dB = (float)(ssB * 0x1p-32);
        int rowl = (r & 3) + 8 * (r >> 2) + 4 * half;
        buf[wv * 1024 + rowl * 32 + (lane & 31)] = dA;
        buf[(wv + 4) * 1024 + rowl * 32 + (lane & 31)] = dB;
      }
    }
    if (wv >= 4 && c > 0) {
      const int tb = (c - 1) * 8;
      const float* buf = d2buf[(c - 1) & 1];
      for (int tl = 0; tl < 8; ++tl) {
        const int t = tb + tl;
#pragma unroll
        for (int q = 0; q < 4; ++q) {
          float d2 = buf[tl * 1024 + (sgrp * 4 + q) * 32 + scol];
          float i2 = __fadd_rn(d2, b2r);
          v2[q] = __fadd_rn(v2[q], i2);
          bool s2 = (v2[q] >= 1.0f);
          v2[q] = s2 ? (v2[q] - 1.0f) : v2[q];
          ull m = __ballot(s2);                    // lo32: even sgrp, hi32: odd
          if (lane == 0)
            masks2[((size_t)t * BB + rowtile * 32 + sgrp * 4 + q) * 8 + stripe]
                = (unsigned)m;
          else if (lane == 32)
            masks2[((size_t)t * BB + rowtile * 32 + sgrp * 4 + q) * 8 + stripe]
                = (unsigned)(m >> 32);
        }
      }
    }
    __syncthreads();
  }
}

// ---- layer 3: D3[t] = S2[t] @ W3^T, exact i8 MFMA. Block: 32 rows x 4 t.
__global__ __launch_bounds__(256) void phase_l3(const signed char* __restrict__ W3d,
    const unsigned* __restrict__ masks2, float* __restrict__ D3)
{
  __shared__ __align__(16) signed char Bl[32768];
  const int bid = blockIdx.x;
  const int rowtile = bid & 31, tgrp = bid >> 5;
  const int tid = threadIdx.x, lane = tid & 63, wv = tid >> 6;
  const int half = lane >> 5;
  const int t = tgrp * 4 + wv;
  const int row = rowtile * 32 + (lane & 31);

  {
    const uint4* src = (const uint4*)W3d;
    uint4* dst = (uint4*)Bl;
#pragma unroll
    for (int i = 0; i < 8; ++i) dst[tid + 256 * i] = src[tid + 256 * i];
  }

  unsigned words[8];
  {
    const unsigned* mp = masks2 + ((size_t)t * BB + row) * 8;
#pragma unroll
    for (int k = 0; k < 8; ++k) words[k] = mp[k];
  }
  __syncthreads();

  const signed char* bbase = Bl + half * 512 + (lane & 31) * 16;
  v16i acc[4];
#pragma unroll
  for (int d = 0; d < 4; ++d) acc[d] = (v16i){0,0,0,0,0,0,0,0,0,0,0,0,0,0,0,0};

#pragma unroll
  for (int c8 = 0; c8 < 8; ++c8) {
    v4i a = expand_bits((words[c8] >> (half * 16)) & 0xFFFFu);
#pragma unroll
    for (int d = 0; d < 4; ++d) {
      v4i b = *(const v4i*)(bbase + ((d * 8 + c8) * 2) * 512);
      acc[d] = __builtin_amdgcn_mfma_i32_32x32x32_i8(a, b, acc[d], 0, 0, 0);
    }
  }

  const int col = lane & 31;
#pragma unroll
  for (int r = 0; r < 16; ++r) {
    int slo = acc[0][r] + (acc[1][r] << 8);
    int shi = acc[2][r] + (acc[3][r] << 8);
    double ss = fma((double)shi, 65536.0, (double)slo);
    float d3v = (float)(ss * 0x1p-32);
    int rowl = (r & 3) + 8 * (r >> 2) + 4 * half;
    int grow = rowtile * 32 + rowl;
    if (col < CC) D3[((size_t)t * BB + grow) * CC + col] = d3v;
  }
}

// ---- v3/acc scan + output. thread=(row,c); 4-deep prefetch ring; grid 72.
__global__ __launch_bounds__(256) void phase_v3(const float* __restrict__ D3,
    const float* __restrict__ b3, float* __restrict__ out)
{
  int g = blockIdx.x * 256 + threadIdx.x;         // [0, 18432)
  int row = g / CC, c = g - row * CC;
  const float b3r = b3[c];
  float v3 = 0.f, acc = 0.f;
  float buf[4];
#pragma unroll
  for (int p = 0; p < 4; ++p) buf[p] = D3[(size_t)p * (BB * CC) + g];
  for (int t = 0; t < TT; ++t) {
    float d3 = buf[t & 3];
    if (t + 4 < TT) buf[t & 3] = D3[(size_t)(t + 4) * (BB * CC) + g];
    float i3 = __fadd_rn(d3, b3r);
    v3 = __fadd_rn(v3, i3);
    bool s3 = (v3 >= 1.0f);  v3 = s3 ? (v3 - 1.0f) : v3;
    acc = __fadd_rn(acc, s3 ? 1.0f : 0.0f);
  }
  out[g] = acc * (1.0f / TT);
}

extern "C" void kernel_launch(void* const* d_in, const int* in_sizes, int n_in,
                              void* d_out, int out_size, void* d_ws, size_t ws_size,
                              hipStream_t stream)
{
  (void)in_sizes; (void)n_in; (void)out_size; (void)ws_size;
  const float* x  = (const float*)d_in[0];
  const float* W1 = (const float*)d_in[1];
  const float* b1 = (const float*)d_in[2];
  const float* W2 = (const float*)d_in[3];
  const float* b2 = (const float*)d_in[4];
  const float* W3 = (const float*)d_in[5];
  const float* b3 = (const float*)d_in[6];
  // d_in[7] = repeat (structurally 1 for this problem shape)
  float* out = (float*)d_out;
  char*  ws  = (char*)d_ws;

  signed char* dig    = (signed char*)(ws + WS_DIG);
  signed char* w3dig  = (signed char*)(ws + WS_W3D);
  ull*         masks  = (ull*)(ws + WS_MASK);
  unsigned*    masks2 = (unsigned*)(ws + WS_MASK2);
  float*       D3     = (float*)(ws + WS_D3);

  prep_digits<<<2048, 256, 0, stream>>>(W2, dig);
  prep_w3dig<<<128, 256, 0, stream>>>(W3, w3dig);
  phase_s1<<<1024, 256, 0, stream>>>(x, W1, b1, masks);
  phase_gemmscan<<<256, 512, 0, stream>>>(dig, masks, b2, masks2);
  phase_l3<<<1024, 256, 0, stream>>>(w3dig, masks2, D3);
  phase_v3<<<72, 256, 0, stream>>>(D3, b3, out);
}